// Round 23
// baseline (226.671 us; speedup 1.0000x reference)
//
#include <hip/hip_runtime.h>

// VQ-VAE VectorQuantizer fwd. K=1024, E=64, N=T*B=65536.
// 3-tier argmin. Tier-1: single-term bf16 MFMA coarse scan (GAP1=1.5e-4,
// flag rate ~10%) -> tier-2 fp32 exact -> tier-3 fp64 (fp32-gap < GAP2).
// R23 (tier-2 rebuild #3): R21/R22 issued 1024 scalar loads/batch in 256
// 4-deep dependency groups with ~1 wave/SIMD -> every L2 wait exposed
// (68us at 9% VALU). Now: float4-packed transpose cbT4[e4*K+k] (1 coalesced
// 16B load replaces 4 scalar) + 8 rows/batch (each load feeds 32 FMA, 8
// independent chains) -> 256 loads/batch, compute-dominated.
// Scores t = ||c||^2 - 2 x.c; codebook pre-scaled by -2, ||c||^2 in C-init.
// MFMA: A = codebook frag, B = x frag -> D(lane l, reg r) =
// score(code = t*16 + (l>>4)*4 + r, row = base + (l&15)).

#define KC 1024
#define ED 64
#define NR 65536
#define NE (NR * ED)
#define GAP1 1.5e-4f
#define GAP2 2e-6f

typedef __attribute__((ext_vector_type(8))) short short8;
typedef __attribute__((ext_vector_type(4))) float f32x4;

__device__ __forceinline__ unsigned short bf16rne(float f) {
    unsigned u = __builtin_bit_cast(unsigned, f);
    return (unsigned short)((u + 0x7fffu + ((u >> 16) & 1u)) >> 16);
}

// Pack tile records (stride 192 short8 = 3KB) + ee[] + cbT4 (float4-packed
// transposed codebook: cbT4[e4*KC + k] = cb[k][e4*4 .. e4*4+3]) + zero ctrs.
// Record t: j=0,1 = bf16(-2*c) for e in [0,32),[32,64); elem (g=l>>4,r)
// <-> e = j*32 + g*8 + r (same bijection as x frags); j=2: f32x4 ||c||^2
// (reg r <-> code t*16+(l>>4)*4+r) bitcast short8. ee[code] = ||c||^2 fp32.
__global__ __launch_bounds__(256) void k_pack(const float* __restrict__ cb,
        short8* __restrict__ cbt, float* __restrict__ ee,
        float4* __restrict__ cbT4, unsigned* __restrict__ counts,
        unsigned* __restrict__ flagcnt, unsigned* __restrict__ flagcnt2) {
    const int u = blockIdx.x * 256 + threadIdx.x;
    if (u < 1024) counts[u] = 0u;
    if (u == 1024) *flagcnt = 0u;
    if (u == 1025) *flagcnt2 = 0u;
    for (int v = u; v < 16384; v += 12288) {      // cbT4 fill: v = e4*KC + k
        const int e4 = v >> 10, k = v & 1023;
        cbT4[v] = ((const float4*)(cb + (size_t)k * ED))[e4];
    }
    if (u >= 64 * 3 * 64) return;
    const int t = u / 192, rem = u % 192, j = rem / 64, l = rem % 64;
    const int g = l >> 4;
    if (j < 2) {
        const int code = t * 16 + (l & 15);
        const float* c = cb + (size_t)code * ED;
        short8 o;
#pragma unroll
        for (int r = 0; r < 8; ++r)
            o[r] = (short)bf16rne(-2.f * c[j * 32 + g * 8 + r]);
        cbt[u] = o;
    } else {
        f32x4 o;
#pragma unroll
        for (int r = 0; r < 4; ++r) {
            const float4* c4 = (const float4*)(cb + (size_t)(t * 16 + g * 4 + r) * ED);
            float s0 = 0.f, s1 = 0.f, s2 = 0.f, s3 = 0.f;
#pragma unroll
            for (int i = 0; i < 16; ++i) {
                const float4 c = c4[i];
                s0 = fmaf(c.x, c.x, s0); s1 = fmaf(c.y, c.y, s1);
                s2 = fmaf(c.z, c.z, s2); s3 = fmaf(c.w, c.w, s3);
            }
            o[r] = (s0 + s1) + (s2 + s3);
            ee[t * 16 + g * 4 + r] = o[r];   // 16 threads write same value
        }
        cbt[u] = __builtin_bit_cast(short8, o);
    }
}

// 512 blocks x 512 thr (8 waves = 2 row-groups x 4 K-quarters), 128 rows
// per block, 64 rows/wave. Phase 1: x -> bf16 frags (hi only) into LDS +
// fp32 ||x||^2 partials. Phase 2: wave (rg,kh) scans tiles [kh*16,+16):
// 3 loads + 8 MFMA + min-track per tile. Phase 3: shfl g-merge; waves 0-1
// merge kh slices (ascending k tie-break), write idx/fidx/histogram/flag/
// SSE (d^2 = best + ||x||^2). Phase 4: cooperative qout gather from fidx.
__global__ __launch_bounds__(512) void k_argmin(
        const float* __restrict__ in, const short8* __restrict__ cbt,
        const float* __restrict__ cb, int* __restrict__ idx,
        float* __restrict__ qout, unsigned* __restrict__ counts,
        unsigned* __restrict__ flagcnt, unsigned* __restrict__ flaglist,
        double* __restrict__ pblk) {
    __shared__ short8 xs[2][8][64];               // 16 KB
    __shared__ float rx2p[4][128];                // 2 KB
    __shared__ float sb[8][4][16], sb2[8][4][16];
    __shared__ int   sk[8][4][16];                // 6 KB
    __shared__ int   fidx[128];
    __shared__ double sred[2];

    const int tid = threadIdx.x;
    const int l = tid & 63;
    const int wid = tid >> 6;                     // 0..7
    const int g = l >> 4;
    const int col = l & 15;
    const int rowBase = blockIdx.x * 128;

    // Phase 1: thread (row=tid&127, ob=tid>>7) converts e in {hh*32+ob*8+j}
    // (16 elems) of its row; ll = ob*16 + (row&15), slot = rt*2 + hh.
    {
        const int row = tid & 127;
        const int ob = tid >> 7;                  // 0..3 (== g of the frag)
        const int rg = row >> 6;
        const int r6 = row & 63;
        const int rt = r6 >> 4;
        const int ll = ob * 16 + (r6 & 15);
        float part = 0.f;
#pragma unroll
        for (int hh = 0; hh < 2; ++hh) {
            short8 H;
#pragma unroll
            for (int j = 0; j < 8; ++j) {
                const float x = in[(size_t)(hh * 32 + ob * 8 + j) * NR + rowBase + row];
                H[j] = (short)bf16rne(x);
                part = fmaf(x, x, part);
            }
            xs[rg][rt * 2 + hh][ll] = H;
        }
        rx2p[ob][row] = part;
    }
    __syncthreads();

    // Phase 2: 8 x-frags to regs (32 VGPR), simple tile loop.
    const int rg = wid >> 2, kh = wid & 3;
    short8 xq[4][2];
#pragma unroll
    for (int rt = 0; rt < 4; ++rt)
#pragma unroll
        for (int q = 0; q < 2; ++q)
            xq[rt][q] = xs[rg][rt * 2 + q][l];

    float best[4]  = {3.4e38f, 3.4e38f, 3.4e38f, 3.4e38f};
    float best2[4] = {3.4e38f, 3.4e38f, 3.4e38f, 3.4e38f};
    int bestk[4] = {0, 0, 0, 0};

#pragma unroll 2
    for (int tt = 0; tt < 16; ++tt) {
        const int t = kh * 16 + tt;
        const short8* bp = cbt + (size_t)t * 192 + l;
        const short8 b0 = bp[0], b1 = bp[64];
        const f32x4 e4 = __builtin_bit_cast(f32x4, bp[128]);
#pragma unroll
        for (int rt = 0; rt < 4; ++rt) {
            f32x4 acc = e4;
            acc = __builtin_amdgcn_mfma_f32_16x16x32_bf16(b0, xq[rt][0], acc, 0, 0, 0);
            acc = __builtin_amdgcn_mfma_f32_16x16x32_bf16(b1, xq[rt][1], acc, 0, 0, 0);
#pragma unroll
            for (int r = 0; r < 4; ++r) {
                const float v = acc[r];
                const int k = t * 16 + g * 4 + r;
                best2[rt] = fminf(fmaxf(v, best[rt]), best2[rt]);  // med3
                const bool c = v < best[rt];
                bestk[rt] = c ? k : bestk[rt];
                best[rt]  = fminf(v, best[rt]);
            }
        }
    }

    // Phase 3a: intra-wave g-merge; g==0 writes per-(rg,kh) partials.
#pragma unroll
    for (int rt = 0; rt < 4; ++rt) {
        float b = best[rt], b2 = best2[rt]; int k = bestk[rt];
#pragma unroll
        for (int sh = 16; sh <= 32; sh <<= 1) {
            const float ob  = __shfl_xor(b, sh, 64);
            const float ob2 = __shfl_xor(b2, sh, 64);
            const int   ok  = __shfl_xor(k, sh, 64);
            if (ob < b || (ob == b && ok < k)) { b2 = fminf(b, ob2); k = ok; b = ob; }
            else b2 = fminf(b2, ob);
        }
        if (g == 0) { sb[wid][rt][col] = b; sb2[wid][rt][col] = b2; sk[wid][rt][col] = k; }
    }
    __syncthreads();

    // Phase 3b: waves 0-1 (rg=wid) merge the 4 kh slices; finalize rows.
    if (wid < 2) {
        const int rt = l >> 4, c2 = l & 15;
        float b = sb[wid * 4][rt][c2], b2 = sb2[wid * 4][rt][c2];
        int k = sk[wid * 4][rt][c2];
#pragma unroll
        for (int s = 1; s < 4; ++s) {              // ascending k ranges
            const float ob = sb[wid * 4 + s][rt][c2], ob2 = sb2[wid * 4 + s][rt][c2];
            const int ok = sk[wid * 4 + s][rt][c2];
            if (ob < b || (ob == b && ok < k)) { b2 = fminf(b, ob2); k = ok; b = ob; }
            else b2 = fminf(b2, ob);
        }
        const int lrow = wid * 64 + rt * 16 + c2;
        const int row = rowBase + lrow;
        idx[row] = k;
        fidx[lrow] = k;
        atomicAdd(&counts[k], 1u);
        if (b2 - b < GAP1) {
            const unsigned p = atomicAdd(flagcnt, 1u);
            flaglist[p] = (unsigned)row;
        }
        double d2 = (double)b + (double)((rx2p[0][lrow] + rx2p[1][lrow])
                                       + (rx2p[2][lrow] + rx2p[3][lrow]));
#pragma unroll
        for (int off = 32; off > 0; off >>= 1) d2 += __shfl_down(d2, off, 64);
        if (l == 0) sred[wid] = d2;
    }
    __syncthreads();
    if (tid == 0) pblk[blockIdx.x] = sred[0] + sred[1];

    // Phase 4: cooperative gather; lanes cover 64 consecutive rows.
    {
        const int row = tid & 127;
        const int e0 = tid >> 7;                  // 0..3
        const int k = fidx[row];
        const float4* c4 = (const float4*)(cb + (size_t)k * ED + e0 * 16);
#pragma unroll
        for (int j = 0; j < 4; ++j) {
            const float4 v = c4[j];
            qout[(size_t)(e0 * 16 + j * 4 + 0) * NR + rowBase + row] = v.x;
            qout[(size_t)(e0 * 16 + j * 4 + 1) * NR + rowBase + row] = v.y;
            qout[(size_t)(e0 * 16 + j * 4 + 2) * NR + rowBase + row] = v.z;
            qout[(size_t)(e0 * 16 + j * 4 + 3) * NR + rowBase + row] = v.w;
        }
    }
}

// Tier-2: fp32 exact argmin, 8 flagged rows per wave, one float4 coalesced
// load per (e4, code) feeding 32 FMAs (8 independent chains). x in
// wave-local LDS. Fixes idx/counts/qout; flags fp32-gap < GAP2.
__global__ __launch_bounds__(256) void k_exact32(
        const float* __restrict__ in, const float* __restrict__ cb,
        const float4* __restrict__ cbT4, const float* __restrict__ ee,
        int* __restrict__ idx, float* __restrict__ qout,
        unsigned* __restrict__ counts,
        const unsigned* __restrict__ flagcnt, const unsigned* __restrict__ flaglist,
        unsigned* __restrict__ flagcnt2, unsigned* __restrict__ flaglist2) {
    __shared__ float xls[4][8][64];
    const unsigned nf = *flagcnt;
    const unsigned nbatch = (nf + 7u) >> 3;
    const int l = threadIdx.x & 63;
    const int wid = threadIdx.x >> 6;
    const unsigned wave = blockIdx.x * 4u + (unsigned)wid;
    const unsigned nwave = gridDim.x * 4u;
    for (unsigned bi = wave; bi < nbatch; bi += nwave) {
        int rows[8]; int nr = 0;
#pragma unroll
        for (int j = 0; j < 8; ++j) {
            const unsigned fi = bi * 8u + j;
            rows[j] = (fi < nf) ? (int)flaglist[fi] : -1;
            if (fi < nf) nr = j + 1;
        }
#pragma unroll
        for (int j = 0; j < 8; ++j)
            xls[wid][j][l] = (rows[j] >= 0) ? in[(size_t)l * NR + rows[j]] : 0.f;

        float best[8], best2[8]; int bestk[8];
#pragma unroll
        for (int j = 0; j < 8; ++j) { best[j] = 3.4e38f; best2[j] = 3.4e38f; bestk[j] = 0; }

        for (int ci = 0; ci < 16; ++ci) {
            const int k = ci * 64 + l;              // ascending k per lane
            float s[8] = {0.f, 0.f, 0.f, 0.f, 0.f, 0.f, 0.f, 0.f};
#pragma unroll
            for (int e4 = 0; e4 < 16; ++e4) {
                const float4 c = cbT4[(size_t)e4 * KC + k];   // coalesced 16B
#pragma unroll
                for (int j = 0; j < 8; ++j) {
                    const float4 xv = ((const float4*)xls[wid][j])[e4];
                    s[j] = fmaf(c.x, xv.x,
                           fmaf(c.y, xv.y,
                           fmaf(c.z, xv.z,
                           fmaf(c.w, xv.w, s[j]))));
                }
            }
            const float ek = ee[k];
#pragma unroll
            for (int j = 0; j < 8; ++j) {
                const float t = fmaf(-2.f, s[j], ek);
                const bool c = t < best[j];
                best2[j] = c ? best[j] : fminf(best2[j], t);
                bestk[j] = c ? k : bestk[j];
                best[j]  = c ? t : best[j];
            }
        }
#pragma unroll
        for (int j = 0; j < 8; ++j) {
            float b = best[j], b2 = best2[j]; int bk = bestk[j];
#pragma unroll
            for (int sh = 1; sh < 64; sh <<= 1) {
                const float ob  = __shfl_xor(b, sh, 64);
                const float ob2 = __shfl_xor(b2, sh, 64);
                const int   ok  = __shfl_xor(bk, sh, 64);
                if (ob < b || (ob == b && ok < bk)) { b2 = fminf(b, ob2); bk = ok; b = ob; }
                else b2 = fminf(b2, ob);
            }
            if (j >= nr) continue;
            const int row = rows[j];
            const int old = idx[row];              // uniform across lanes
            if (bk != old) {
                if (l == 0) {
                    idx[row] = bk;
                    atomicSub(&counts[old], 1u);
                    atomicAdd(&counts[bk], 1u);
                }
                qout[(size_t)l * NR + row] = cb[(size_t)bk * ED + l];
            }
            if (l == 0 && b2 - b < GAP2) {
                const unsigned p = atomicAdd(flagcnt2, 1u);
                flaglist2[p] = (unsigned)row;
            }
        }
    }
}

// Tier-3: fp64 exact argmin for tier-2-flagged rows; one wave per row.
__global__ __launch_bounds__(256) void k_exact64(
        const float* __restrict__ in, const float* __restrict__ cb,
        int* __restrict__ idx, float* __restrict__ qout,
        unsigned* __restrict__ counts,
        const unsigned* __restrict__ flagcnt2, const unsigned* __restrict__ flaglist2) {
    const unsigned nf = *flagcnt2;
    const int l = threadIdx.x & 63;
    const unsigned wave = blockIdx.x * 4u + (unsigned)(threadIdx.x >> 6);
    const unsigned nwave = gridDim.x * 4u;
    for (unsigned i = wave; i < nf; i += nwave) {
        const int row = (int)flaglist2[i];
        float x[ED];
#pragma unroll
        for (int e = 0; e < ED; ++e) x[e] = in[(size_t)e * NR + row];
        double best = 1e300; int bestk = 0;
        for (int ci = 0; ci < 16; ++ci) {
            const int k = ci * 64 + l;
            const float* c = cb + (size_t)k * ED;
            double s = 0.0, e2 = 0.0;
            for (int e = 0; e < ED; ++e) {
                const double cv = (double)c[e];
                e2 = fma(cv, cv, e2);
                s  = fma(cv, (double)x[e], s);
            }
            const double t = fma(-2.0, s, e2);
            if (t < best) { best = t; bestk = k; }
        }
        for (int sh = 1; sh < 64; sh <<= 1) {
            const double ob = __shfl_xor(best, sh, 64);
            const int   ok  = __shfl_xor(bestk, sh, 64);
            if (ob < best || (ob == best && ok < bestk)) { best = ob; bestk = ok; }
        }
        const int old = idx[row];
        if (bestk != old) {
            if (l == 0) {
                idx[row] = bestk;
                atomicSub(&counts[old], 1u);
                atomicAdd(&counts[bestk], 1u);
            }
            qout[(size_t)l * NR + row] = cb[(size_t)bestk * ED + l];
        }
    }
}

// Scalars: entropy from final counts + SSE from 512 per-block partials.
__global__ __launch_bounds__(1024) void k_final(const unsigned* __restrict__ counts,
        const double* __restrict__ pblk, float* __restrict__ out) {
    __shared__ double redE[16], redS[16];
    const int tid = threadIdx.x;
    const double p = (double)counts[tid] * (1.0 / 65536.0);
    double term = p * log(p + 1e-10);
    double s = (tid < 512) ? pblk[tid] : 0.0;
#pragma unroll
    for (int off = 32; off > 0; off >>= 1) {
        term += __shfl_down(term, off, 64);
        s    += __shfl_down(s,    off, 64);
    }
    if ((tid & 63) == 0) { redE[tid >> 6] = term; redS[tid >> 6] = s; }
    __syncthreads();
    if (tid == 0) {
        double e = 0.0, ss = 0.0;
        for (int i = 0; i < 16; ++i) { e += redE[i]; ss += redS[i]; }
        out[1 + NE] = (float)exp(-e);                 // perplexity
        const double m = ss * (1.0 / 4194304.0);      // mean((q-x)^2)
        out[0] = (float)(1.25 * m);                   // (1+beta)*m
    }
}

extern "C" void kernel_launch(void* const* d_in, const int* in_sizes, int n_in,
                              void* d_out, int out_size, void* d_ws, size_t ws_size,
                              hipStream_t stream) {
    (void)in_sizes; (void)n_in; (void)out_size; (void)ws_size;
    const float* in = (const float*)d_in[0];
    const float* cb = (const float*)d_in[1];
    float* out = (float*)d_out;

    // ws layout (dword offsets), strictly disjoint -- audited:
    //  [0,1024) counts | [1024] flagcnt | [1025] flagcnt2
    //  [2048,51200)    cbt: 64 tiles x 192 short8 x 4 dw = 49152 dw (192KB)
    //  [51200,52224)   ee (f32[1024])
    //  [83968,149504)  idx | [149504,215040) flaglist | [215040,280576) flaglist2
    //  [280576,281600) pblk: 512 f64 (byte 1122304)
    //  [282624,348160) cbT4: 16384 float4 (256KB, byte 1130496, 16B-aligned)
    unsigned* counts    = (unsigned*)d_ws;
    unsigned* flagcnt   = (unsigned*)d_ws + 1024;
    unsigned* flagcnt2  = (unsigned*)d_ws + 1025;
    short8*   cbt       = (short8*)((float*)d_ws + 2048);
    float*    ee        = (float*)d_ws + 51200;
    int*      idx       = (int*)d_ws + 83968;
    unsigned* flaglist  = (unsigned*)d_ws + 149504;
    unsigned* flaglist2 = (unsigned*)d_ws + 215040;
    double*   pblk      = (double*)((char*)d_ws + 1122304);
    float4*   cbT4      = (float4*)((float*)d_ws + 282624);

    hipLaunchKernelGGL(k_pack,    dim3(48),   dim3(256),  0, stream,
                       cb, cbt, ee, cbT4, counts, flagcnt, flagcnt2);
    hipLaunchKernelGGL(k_argmin,  dim3(512),  dim3(512),  0, stream,
                       in, cbt, cb, idx, out + 1, counts, flagcnt, flaglist, pblk);
    hipLaunchKernelGGL(k_exact32, dim3(1024), dim3(256),  0, stream,
                       in, cb, cbT4, ee, idx, out + 1, counts, flagcnt, flaglist,
                       flagcnt2, flaglist2);
    hipLaunchKernelGGL(k_exact64, dim3(128),  dim3(256),  0, stream,
                       in, cb, idx, out + 1, counts, flagcnt2, flaglist2);
    hipLaunchKernelGGL(k_final,   dim3(1),    dim3(1024), 0, stream,
                       counts, pblk, out);
}

// Round 24
// 79.405 us; speedup vs baseline: 2.8546x; 2.8546x over previous
//
#include <hip/hip_runtime.h>

// VQ-VAE VectorQuantizer fwd. K=1024, E=64, N=T*B=65536.
// 2-tier argmin: 3-term bf16-split MFMA (ch*xh + cl*xh + ch*xl; err ~1e-7,
// GAP1=6e-6, flag count ~1e2) -> fp64 exact re-resolve. R18-R23's 1-term
// coarse pass needed a ~6.5k-row fp32 tier that resisted 4 batching
// shapes (spill/latency walls); reverted to the R17 frame.
// R24: k_argmin moved to 256-thr blocks (1024 blocks x 4 waves, 64 rows,
// wave=K-quarter). 512-thr blocks allocate only 64 VGPR -> per-tile LDS
// remat of the 64-reg xq set (~5us/CU); 256-thr historically allocates 88
// (R4/R8) -> xq genuinely resident. Conversion once/block in LDS; 5KB
// dedup'd records (b0,b1 reused for xl terms); fused epilogue + qout
// gather in-kernel; 4 launches.
// Scores t = ||c||^2 - 2 x.c; codebook pre-scaled by -2, ||c||^2 in C-init.
// MFMA: A = codebook frag, B = x frag -> D(lane l, reg r) =
// score(code = t*16 + (l>>4)*4 + r, row = base + (l&15)).

#define KC 1024
#define ED 64
#define NR 65536
#define NE (NR * ED)
#define GAP1 6e-6f

typedef __attribute__((ext_vector_type(8))) short short8;
typedef __attribute__((ext_vector_type(4))) float f32x4;

__device__ __forceinline__ unsigned short bf16rne(float f) {
    unsigned u = __builtin_bit_cast(unsigned, f);
    return (unsigned short)((u + 0x7fffu + ((u >> 16) & 1u)) >> 16);
}
__device__ __forceinline__ float bf16tof(unsigned short h) {
    return __builtin_bit_cast(float, (unsigned)h << 16);
}

// Pack compact tile records (stride 320 short8 = 5KB) + zero counts/flag.
// Record t: j=0,1 = ch (hi bf16 of -2*c) for e in [0,32),[32,64); j=2,3 =
// cl (lo residual); elem (g=l>>4,r) <-> e = (j&1)*32 + g*8 + r (same
// bijection as the x fragments); j=4: f32x4 ||c||^2 (reg r <-> code
// t*16+(l>>4)*4+r) bitcast short8.
__global__ __launch_bounds__(256) void k_pack(const float* __restrict__ cb,
        short8* __restrict__ cbt, unsigned* __restrict__ counts,
        unsigned* __restrict__ flagcnt) {
    const int u = blockIdx.x * 256 + threadIdx.x;
    if (u < 1024) counts[u] = 0u;
    if (u == 1024) *flagcnt = 0u;
    if (u >= 64 * 5 * 64) return;
    const int t = u / 320, rem = u % 320, j = rem / 64, l = rem % 64;
    const int g = l >> 4;
    if (j < 4) {
        const int code = t * 16 + (l & 15);
        const float* c = cb + (size_t)code * ED;
        const bool lo = (j >= 2);
        short8 o;
#pragma unroll
        for (int r = 0; r < 8; ++r) {
            const int e = (j & 1) * 32 + g * 8 + r;
            const float m2 = -2.f * c[e];
            const unsigned short h = bf16rne(m2);
            o[r] = lo ? (short)bf16rne(m2 - bf16tof(h)) : (short)h;
        }
        cbt[u] = o;
    } else {
        f32x4 o;
#pragma unroll
        for (int r = 0; r < 4; ++r) {
            const float4* c4 = (const float4*)(cb + (size_t)(t * 16 + g * 4 + r) * ED);
            float s0 = 0.f, s1 = 0.f, s2 = 0.f, s3 = 0.f;
#pragma unroll
            for (int i = 0; i < 16; ++i) {
                const float4 c = c4[i];
                s0 = fmaf(c.x, c.x, s0); s1 = fmaf(c.y, c.y, s1);
                s2 = fmaf(c.z, c.z, s2); s3 = fmaf(c.w, c.w, s3);
            }
            o[r] = (s0 + s1) + (s2 + s3);
        }
        cbt[u] = __builtin_bit_cast(short8, o);
    }
}

// 1024 blocks x 256 thr (4 waves = 4 K-quarters), 64 rows/block, exactly
// 4 blocks/CU. Phase 1: cooperative x -> bf16 hi/lo frags into LDS +
// ||x||^2 partials. Phase 2: wave kh holds all 16 x-frags in 64 VGPR
// (resident under the 256-thr budget), scans tiles [kh*16,+16): 5 loads +
// 24 MFMA + min-track (b0,b1 reused for xl). Phase 3: shfl g-merge; wave 0
// merges kh slices (ascending k tie-break), writes idx/fidx/histogram/
// flag/SSE (d^2 = best + ||x||^2). Phase 4: cooperative qout gather.
__global__ __launch_bounds__(256) void k_argmin(
        const float* __restrict__ in, const short8* __restrict__ cbt,
        const float* __restrict__ cb, int* __restrict__ idx,
        float* __restrict__ qout, unsigned* __restrict__ counts,
        unsigned* __restrict__ flagcnt, unsigned* __restrict__ flaglist,
        double* __restrict__ pblk) {
    __shared__ short8 xs[16][64];                 // 16 KB
    __shared__ float rx2p[4][64];                 // 1 KB
    __shared__ float sb[4][4][16], sb2[4][4][16];
    __shared__ int   sk[4][4][16];                // 3 KB
    __shared__ int   fidx[64];

    const int tid = threadIdx.x;
    const int l = tid & 63;
    const int wid = tid >> 6;                     // 0..3 == kh
    const int g = l >> 4;
    const int col = l & 15;
    const int rowBase = blockIdx.x * 64;

    // Phase 1: thread (row=tid&63, ob=tid>>6) converts e in {hh*32+ob*8+j}
    // (16 elems) of its row; ll = ob*16 + (row&15), slot = rt*4 + hh (+2 lo).
    {
        const int row = tid & 63;
        const int ob = tid >> 6;                  // 0..3 (== g of the frag)
        const int rt = row >> 4;
        const int ll = ob * 16 + (row & 15);
        float part = 0.f;
#pragma unroll
        for (int hh = 0; hh < 2; ++hh) {
            short8 H, L;
#pragma unroll
            for (int j = 0; j < 8; ++j) {
                const float x = in[(size_t)(hh * 32 + ob * 8 + j) * NR + rowBase + row];
                const unsigned short hb = bf16rne(x);
                H[j] = (short)hb;
                L[j] = (short)bf16rne(x - bf16tof(hb));
                part = fmaf(x, x, part);
            }
            xs[rt * 4 + hh][ll] = H;
            xs[rt * 4 + 2 + hh][ll] = L;
        }
        rx2p[ob][row] = part;
    }
    __syncthreads();

    // Phase 2: all 16 x-frags to regs (64 VGPR, resident), simple tile loop.
    const int kh = wid;
    short8 xq[4][4];
#pragma unroll
    for (int rt = 0; rt < 4; ++rt)
#pragma unroll
        for (int q = 0; q < 4; ++q)
            xq[rt][q] = xs[rt * 4 + q][l];

    float best[4]  = {3.4e38f, 3.4e38f, 3.4e38f, 3.4e38f};
    float best2[4] = {3.4e38f, 3.4e38f, 3.4e38f, 3.4e38f};
    int bestk[4] = {0, 0, 0, 0};

#pragma unroll 2
    for (int tt = 0; tt < 16; ++tt) {
        const int t = kh * 16 + tt;
        const short8* bp = cbt + (size_t)t * 320 + l;
        const short8 b0 = bp[0], b1 = bp[64], b2 = bp[128], b3 = bp[192];
        const f32x4 e4 = __builtin_bit_cast(f32x4, bp[256]);
#pragma unroll
        for (int rt = 0; rt < 4; ++rt) {
            f32x4 acc = e4;
            acc = __builtin_amdgcn_mfma_f32_16x16x32_bf16(b0, xq[rt][0], acc, 0, 0, 0);
            acc = __builtin_amdgcn_mfma_f32_16x16x32_bf16(b1, xq[rt][1], acc, 0, 0, 0);
            acc = __builtin_amdgcn_mfma_f32_16x16x32_bf16(b2, xq[rt][0], acc, 0, 0, 0);
            acc = __builtin_amdgcn_mfma_f32_16x16x32_bf16(b3, xq[rt][1], acc, 0, 0, 0);
            acc = __builtin_amdgcn_mfma_f32_16x16x32_bf16(b0, xq[rt][2], acc, 0, 0, 0);
            acc = __builtin_amdgcn_mfma_f32_16x16x32_bf16(b1, xq[rt][3], acc, 0, 0, 0);
#pragma unroll
            for (int r = 0; r < 4; ++r) {
                const float v = acc[r];
                const int k = t * 16 + g * 4 + r;
                best2[rt] = fminf(fmaxf(v, best[rt]), best2[rt]);  // med3
                const bool c = v < best[rt];
                bestk[rt] = c ? k : bestk[rt];
                best[rt]  = fminf(v, best[rt]);
            }
        }
    }

    // Phase 3a: intra-wave g-merge; g==0 writes per-kh partials.
#pragma unroll
    for (int rt = 0; rt < 4; ++rt) {
        float b = best[rt], b2 = best2[rt]; int k = bestk[rt];
#pragma unroll
        for (int sh = 16; sh <= 32; sh <<= 1) {
            const float ob  = __shfl_xor(b, sh, 64);
            const float ob2 = __shfl_xor(b2, sh, 64);
            const int   ok  = __shfl_xor(k, sh, 64);
            if (ob < b || (ob == b && ok < k)) { b2 = fminf(b, ob2); k = ok; b = ob; }
            else b2 = fminf(b2, ob);
        }
        if (g == 0) { sb[wid][rt][col] = b; sb2[wid][rt][col] = b2; sk[wid][rt][col] = k; }
    }
    __syncthreads();

    // Phase 3b: wave 0 merges the 4 kh slices; lane l owns row rt*16+c2.
    if (wid == 0) {
        const int rt = l >> 4, c2 = l & 15;
        float b = sb[0][rt][c2], b2 = sb2[0][rt][c2]; int k = sk[0][rt][c2];
#pragma unroll
        for (int s = 1; s < 4; ++s) {              // ascending k ranges
            const float ob = sb[s][rt][c2], ob2 = sb2[s][rt][c2];
            const int ok = sk[s][rt][c2];
            if (ob < b || (ob == b && ok < k)) { b2 = fminf(b, ob2); k = ok; b = ob; }
            else b2 = fminf(b2, ob);
        }
        const int lrow = rt * 16 + c2;
        const int row = rowBase + lrow;
        idx[row] = k;
        fidx[lrow] = k;
        atomicAdd(&counts[k], 1u);
        if (b2 - b < GAP1) {
            const unsigned p = atomicAdd(flagcnt, 1u);
            flaglist[p] = (unsigned)row;
        }
        double d2 = (double)b + (double)((rx2p[0][lrow] + rx2p[1][lrow])
                                       + (rx2p[2][lrow] + rx2p[3][lrow]));
#pragma unroll
        for (int off = 32; off > 0; off >>= 1) d2 += __shfl_down(d2, off, 64);
        if (l == 0) pblk[blockIdx.x] = d2;
    }
    __syncthreads();

    // Phase 4: cooperative gather; lanes cover 64 consecutive rows per e.
    {
        const int row = tid & 63;
        const int e0 = tid >> 6;                  // 0..3
        const int k = fidx[row];
        const float4* c4 = (const float4*)(cb + (size_t)k * ED + e0 * 16);
#pragma unroll
        for (int j = 0; j < 4; ++j) {
            const float4 v = c4[j];
            qout[(size_t)(e0 * 16 + j * 4 + 0) * NR + rowBase + row] = v.x;
            qout[(size_t)(e0 * 16 + j * 4 + 1) * NR + rowBase + row] = v.y;
            qout[(size_t)(e0 * 16 + j * 4 + 2) * NR + rowBase + row] = v.z;
            qout[(size_t)(e0 * 16 + j * 4 + 3) * NR + rowBase + row] = v.w;
        }
    }
}

// fp64 exact argmin for flagged rows (count ~1e2); one wave per row;
// adjusts histogram and rewrites the row's qout column on change.
__global__ __launch_bounds__(256) void k_exact64(
        const float* __restrict__ in, const float* __restrict__ cb,
        int* __restrict__ idx, float* __restrict__ qout,
        unsigned* __restrict__ counts,
        const unsigned* __restrict__ flagcnt, const unsigned* __restrict__ flaglist) {
    const unsigned nf = *flagcnt;
    const int l = threadIdx.x & 63;
    const unsigned wave = blockIdx.x * 4u + (unsigned)(threadIdx.x >> 6);
    const unsigned nwave = gridDim.x * 4u;
    for (unsigned i = wave; i < nf; i += nwave) {
        const int row = (int)flaglist[i];
        float x[ED];
#pragma unroll
        for (int e = 0; e < ED; ++e) x[e] = in[(size_t)e * NR + row];
        double best = 1e300; int bestk = 0;
        for (int ci = 0; ci < 16; ++ci) {
            const int k = ci * 64 + l;              // ascending k per lane
            const float* c = cb + (size_t)k * ED;
            double s = 0.0, e2 = 0.0;
            for (int e = 0; e < ED; ++e) {
                const double cv = (double)c[e];
                e2 = fma(cv, cv, e2);
                s  = fma(cv, (double)x[e], s);
            }
            const double t = fma(-2.0, s, e2);
            if (t < best) { best = t; bestk = k; }
        }
        for (int sh = 1; sh < 64; sh <<= 1) {
            const double ob = __shfl_xor(best, sh, 64);
            const int   ok  = __shfl_xor(bestk, sh, 64);
            if (ob < best || (ob == best && ok < bestk)) { best = ob; bestk = ok; }
        }
        const int old = idx[row];                  // same addr all lanes
        if (bestk != old) {
            if (l == 0) {
                idx[row] = bestk;
                atomicSub(&counts[old], 1u);
                atomicAdd(&counts[bestk], 1u);
            }
            qout[(size_t)l * NR + row] = cb[(size_t)bestk * ED + l];
        }
    }
}

// Scalars: entropy from final counts + SSE from 1024 per-block partials
// (fixed-order tree -> deterministic).
__global__ __launch_bounds__(1024) void k_final(const unsigned* __restrict__ counts,
        const double* __restrict__ pblk, float* __restrict__ out) {
    __shared__ double redE[16], redS[16];
    const int tid = threadIdx.x;
    const double p = (double)counts[tid] * (1.0 / 65536.0);
    double term = p * log(p + 1e-10);
    double s = pblk[tid];
#pragma unroll
    for (int off = 32; off > 0; off >>= 1) {
        term += __shfl_down(term, off, 64);
        s    += __shfl_down(s,    off, 64);
    }
    if ((tid & 63) == 0) { redE[tid >> 6] = term; redS[tid >> 6] = s; }
    __syncthreads();
    if (tid == 0) {
        double e = 0.0, ss = 0.0;
        for (int i = 0; i < 16; ++i) { e += redE[i]; ss += redS[i]; }
        out[1 + NE] = (float)exp(-e);                 // perplexity
        const double m = ss * (1.0 / 4194304.0);      // mean((q-x)^2)
        out[0] = (float)(1.25 * m);                   // (1+beta)*m
    }
}

extern "C" void kernel_launch(void* const* d_in, const int* in_sizes, int n_in,
                              void* d_out, int out_size, void* d_ws, size_t ws_size,
                              hipStream_t stream) {
    (void)in_sizes; (void)n_in; (void)out_size; (void)ws_size;
    const float* in = (const float*)d_in[0];
    const float* cb = (const float*)d_in[1];
    float* out = (float*)d_out;

    // ws layout (dword offsets), strictly disjoint -- audited end-to-end:
    //  [0,1024) counts | [1024] flagcnt
    //  [2048,83968)    cbt: 64 tiles x 320 short8 x 4 dw = 81920 dw (320KB)
    //  [83968,149504)  idx (65536)
    //  [149504,215040) flaglist (65536)
    //  [215040,217088) pblk: 1024 f64 (byte 860160, 8B-aligned)
    unsigned* counts   = (unsigned*)d_ws;
    unsigned* flagcnt  = (unsigned*)d_ws + 1024;
    short8*   cbt      = (short8*)((float*)d_ws + 2048);
    int*      idx      = (int*)d_ws + 83968;
    unsigned* flaglist = (unsigned*)d_ws + 149504;
    double*   pblk     = (double*)((char*)d_ws + 860160);

    hipLaunchKernelGGL(k_pack,    dim3(80),   dim3(256),  0, stream,
                       cb, cbt, counts, flagcnt);
    hipLaunchKernelGGL(k_argmin,  dim3(1024), dim3(256),  0, stream,
                       in, cbt, cb, idx, out + 1, counts, flagcnt, flaglist, pblk);
    hipLaunchKernelGGL(k_exact64, dim3(128),  dim3(256),  0, stream,
                       in, cb, idx, out + 1, counts, flagcnt, flaglist);
    hipLaunchKernelGGL(k_final,   dim3(1),    dim3(1024), 0, stream,
                       counts, pblk, out);
}